// Round 8
// baseline (219.974 us; speedup 1.0000x reference)
//
#include <hip/hip_runtime.h>
#include <hip/hip_bf16.h>

#define C 128
#define G 8
#define KNN 16
#define QB 4
#define EPS 1e-5f

typedef unsigned short u16;
typedef __attribute__((ext_vector_type(8))) short short8;   // 8 bf16 = 4 VGPRs
typedef __attribute__((ext_vector_type(4))) float float4v;  // MFMA accumulator

union frag_u { short8 v; u16 u[8]; unsigned d[4]; };

__device__ inline u16 f2bf(float f) {
    unsigned u = __builtin_bit_cast(unsigned, f);
    unsigned r = (u + 0x7fffu + ((u >> 16) & 1u)) >> 16;
    return (u16)r;
}
__device__ inline float bf2f(u16 h) {
    unsigned u = ((unsigned)h) << 16;
    return __builtin_bit_cast(float, u);
}
// packed RNE f32x2 -> bf16x2 (v_cvt_pk_bf16_f32 on gfx950); low = a, high = b
__device__ inline unsigned pkbf(float a, float b) {
    __hip_bfloat162 h = __float22bfloat162_rn(float2{a, b});
    unsigned r;
    __builtin_memcpy(&r, &h, 4);
    return r;
}

// ---------------------------------------------------------------------------
// Prep: swizzle weights into MFMA B-frag bf16 layout.
//  128x128 W -> [cb 8][kk 4][quad 4][lan 16][j 8]; elem = W[kk*32+quad*8+j][cb*16+lan]
//  Ww1 (128x8), Wp2' = Wp2@Ww1 (128x8): single-cb frag (4096), zero lan>=8.
//  Wp1 (3x128): K=32-padded B-frag [cb 8][quad 4][lan 16][j 8] (4096), k<3 only.
//  cw1[g] = bp2 . Ww1[:,g].
// 19 blocks.
// ---------------------------------------------------------------------------
__global__ __launch_bounds__(256) void prep_w(
    const float* __restrict__ Wk, const float* __restrict__ Wv,
    const float* __restrict__ Wq, const float* __restrict__ Wp2,
    const float* __restrict__ Ww1, const float* __restrict__ Wp1,
    const float* __restrict__ bp2,
    u16* __restrict__ dst, float* __restrict__ cw1)
{
    const int b = blockIdx.x, t = threadIdx.x;
    if (b < 16) {
        const int mi = b >> 2, qt = b & 3;
        const float* W = mi == 0 ? Wk : mi == 1 ? Wv : mi == 2 ? Wq : Wp2;
        u16* d = dst + mi * 16384;
        for (int e = qt * 4096 + t; e < (qt + 1) * 4096; e += 256) {
            const int k = e >> 7, n = e & 127;
            const int cb = n >> 4, lan = n & 15;
            const int kk = k >> 5, quad = (k >> 3) & 3, j = k & 7;
            d[(((cb * 4 + kk) * 4 + quad) * 16 + lan) * 8 + j] = f2bf(W[e]);
        }
    } else if (b == 16) {
        u16* d = dst + 4 * 16384;
        for (int e = t; e < 4096; e += 256) {
            const int j = e & 7, lan = (e >> 3) & 15;
            const int quad = (e >> 7) & 3, kk = e >> 9;
            const int k = kk * 32 + quad * 8 + j;
            d[e] = lan < 8 ? f2bf(Ww1[k * G + lan]) : (u16)0;
        }
    } else if (b == 17) {
        // Wp2' = Wp2 @ Ww1 -> B-frag; cw1 = bp2 @ Ww1
        u16* d = dst + 4 * 16384 + 4096;
        for (int e = t; e < 4096; e += 256) d[e] = 0;
        __syncthreads();
#pragma unroll
        for (int it = 0; it < 4; it++) {
            const int k = it * 32 + (t >> 3), g = t & 7;
            float a = 0.f;
            for (int i = 0; i < C; i++)
                a = fmaf(Wp2[k * C + i], Ww1[i * G + g], a);
            const int kk = k >> 5, quad = (k >> 3) & 3, j = k & 7;
            d[((kk * 4 + quad) * 16 + g) * 8 + j] = f2bf(a);
        }
        if (t < G) {
            float a = 0.f;
            for (int i = 0; i < C; i++) a = fmaf(bp2[i], Ww1[i * G + t], a);
            cw1[t] = a;
        }
    } else {
        // Wp1 (3 x 128) -> K=32-padded B-frag
        u16* d = dst + 4 * 16384 + 2 * 4096;
        for (int e = t; e < 4096; e += 256) d[e] = 0;
        __syncthreads();
        if (t < 128) {
            const int cb = t >> 4, lan = t & 15;
#pragma unroll
            for (int j = 0; j < 3; j++)
                d[(cb * 64 + lan) * 8 + j] = f2bf(Wp1[j * C + cb * 16 + lan]);
        }
    }
}

// ---------------------------------------------------------------------------
// Fused projections. Blocks [0,nkv): context -> v (NxC bf16) + K' = k@Ww1 (NxG).
// Blocks [nkv,..): query -> Q' = q@Ww1 (MxG). Full k and q never stored.
// ---------------------------------------------------------------------------
__global__ __launch_bounds__(256) void proj_all(
    const float* __restrict__ Xc, const float* __restrict__ Xq,
    const u16* __restrict__ PWk, const float* __restrict__ bk,
    const float* __restrict__ gk, const float* __restrict__ betak,
    const u16* __restrict__ PWv, const float* __restrict__ bv,
    const u16* __restrict__ PWq, const float* __restrict__ bq,
    const float* __restrict__ gq, const float* __restrict__ betaq,
    const u16* __restrict__ PWw1b,
    u16* __restrict__ vout, u16* __restrict__ Kp, u16* __restrict__ Qp,
    int nkv)
{
    __shared__ __align__(16) u16 Xs[64 * 136];
    const int t = threadIdx.x;
    const int w = t >> 6, l = t & 63;
    const int quad = l >> 4, lan = l & 15;
    const bool isq = (int)blockIdx.x >= nkv;
    const long long row0 = (long long)(isq ? blockIdx.x - nkv : blockIdx.x) * 64;
    const float* X = isq ? Xq : Xc;

    // stage X tile -> bf16 LDS (packed cvt)
    {
        const float4* Xv = (const float4*)(X + row0 * C);
#pragma unroll
        for (int i = 0; i < 8; i++) {
            const int e = t + 256 * i;
            const int r = e >> 5, c4 = e & 31;
            const float4 f = Xv[e];
            uint2 p;
            p.x = pkbf(f.x, f.y);
            p.y = pkbf(f.z, f.w);
            *(uint2*)(&Xs[r * 136 + c4 * 4]) = p;
        }
    }
    __syncthreads();

    if (!isq) {
        // ---- v pass (bias only), packed bf16 in regs ----
        unsigned vp[2][4][2];
        {
            short8 Bf[2][4];
#pragma unroll
            for (int ct = 0; ct < 2; ct++) {
                const int cb = w * 2 + ct;
#pragma unroll
                for (int kk = 0; kk < 4; kk++)
                    Bf[ct][kk] = *(const short8*)(PWv + (((cb * 4 + kk) * 4 + quad) * 16 + lan) * 8);
            }
            float4v acc[2][4];
#pragma unroll
            for (int ct = 0; ct < 2; ct++)
#pragma unroll
                for (int rt = 0; rt < 4; rt++) acc[ct][rt] = (float4v)0.f;
#pragma unroll
            for (int rt = 0; rt < 4; rt++)
#pragma unroll
                for (int kk = 0; kk < 4; kk++) {
                    const short8 A = *(const short8*)(&Xs[(rt * 16 + lan) * 136 + kk * 32 + quad * 8]);
#pragma unroll
                    for (int ct = 0; ct < 2; ct++)
                        acc[ct][rt] = __builtin_amdgcn_mfma_f32_16x16x32_bf16(
                            A, Bf[ct][kk], acc[ct][rt], 0, 0, 0);
                }
#pragma unroll
            for (int ct = 0; ct < 2; ct++) {
                const float bb = bv[w * 32 + ct * 16 + lan];
#pragma unroll
                for (int rt = 0; rt < 4; rt++)
#pragma unroll
                    for (int h = 0; h < 2; h++)
                        vp[ct][rt][h] = pkbf(acc[ct][rt][2 * h] + bb, acc[ct][rt][2 * h + 1] + bb);
            }
        }
        // ---- k pass (bn+relu), kept in regs ----
        float4v acck[2][4];
        {
            short8 Bf[2][4];
#pragma unroll
            for (int ct = 0; ct < 2; ct++) {
                const int cb = w * 2 + ct;
#pragma unroll
                for (int kk = 0; kk < 4; kk++)
                    Bf[ct][kk] = *(const short8*)(PWk + (((cb * 4 + kk) * 4 + quad) * 16 + lan) * 8);
            }
#pragma unroll
            for (int ct = 0; ct < 2; ct++)
#pragma unroll
                for (int rt = 0; rt < 4; rt++) acck[ct][rt] = (float4v)0.f;
#pragma unroll
            for (int rt = 0; rt < 4; rt++)
#pragma unroll
                for (int kk = 0; kk < 4; kk++) {
                    const short8 A = *(const short8*)(&Xs[(rt * 16 + lan) * 136 + kk * 32 + quad * 8]);
#pragma unroll
                    for (int ct = 0; ct < 2; ct++)
                        acck[ct][rt] = __builtin_amdgcn_mfma_f32_16x16x32_bf16(
                            A, Bf[ct][kk], acck[ct][rt], 0, 0, 0);
                }
        }
        __syncthreads();   // Xs A-reads done

        // k epilogue: bn+relu -> Xs (row-major bf16, A-frag-readable)
#pragma unroll
        for (int ct = 0; ct < 2; ct++) {
            const int cg = w * 32 + ct * 16 + lan;
            const float bb = bk[cg];
            const float sc = gk[cg] * rsqrtf(1.f + EPS);
            const float sh = betak[cg];
#pragma unroll
            for (int rt = 0; rt < 4; rt++)
#pragma unroll
                for (int reg = 0; reg < 4; reg++) {
                    float y = (acck[ct][rt][reg] + bb) * sc + sh;
                    y = y > 0.f ? y : 0.f;
                    Xs[(rt * 16 + quad * 4 + reg) * 136 + cg] = f2bf(y);
                }
        }
        __syncthreads();

        // K' = k @ Ww1 : wave w handles rows [16w,16w+16)
        {
            short8 Bw[4];
#pragma unroll
            for (int kk = 0; kk < 4; kk++)
                Bw[kk] = *(const short8*)(PWw1b + ((kk * 4 + quad) * 16 + lan) * 8);
            float4v ka = (float4v)0.f;
#pragma unroll
            for (int kk = 0; kk < 4; kk++) {
                const short8 A = *(const short8*)(&Xs[(w * 16 + lan) * 136 + kk * 32 + quad * 8]);
                ka = __builtin_amdgcn_mfma_f32_16x16x32_bf16(A, Bw[kk], ka, 0, 0, 0);
            }
            if (lan < G) {
#pragma unroll
                for (int reg = 0; reg < 4; reg++)
                    Kp[(row0 + w * 16 + quad * 4 + reg) * G + lan] = f2bf(ka[reg]);
            }
        }
        __syncthreads();   // Xs K'-reads done

        // v epilogue (unpack) -> Xs -> coalesced store
#pragma unroll
        for (int ct = 0; ct < 2; ct++) {
            const int cg = w * 32 + ct * 16 + lan;
#pragma unroll
            for (int rt = 0; rt < 4; rt++)
#pragma unroll
                for (int h = 0; h < 2; h++) {
                    Xs[(rt * 16 + quad * 4 + 2 * h) * 136 + cg]     = (u16)(vp[ct][rt][h] & 0xffffu);
                    Xs[(rt * 16 + quad * 4 + 2 * h + 1) * 136 + cg] = (u16)(vp[ct][rt][h] >> 16);
                }
        }
        __syncthreads();
#pragma unroll
        for (int i = 0; i < 4; i++) {
            const int e = t + 256 * i;
            const int r = e >> 4, cc = (e & 15) * 8;
            *(short8*)(vout + (row0 + r) * C + cc) = *(const short8*)(&Xs[r * 136 + cc]);
        }
    } else {
        // ---- q path: q = relu(bn(xq@Wq+bq)) in regs -> Xs -> Q' = q@Ww1 ----
        float4v acc[2][4];
        {
            short8 Bf[2][4];
#pragma unroll
            for (int ct = 0; ct < 2; ct++) {
                const int cb = w * 2 + ct;
#pragma unroll
                for (int kk = 0; kk < 4; kk++)
                    Bf[ct][kk] = *(const short8*)(PWq + (((cb * 4 + kk) * 4 + quad) * 16 + lan) * 8);
            }
#pragma unroll
            for (int ct = 0; ct < 2; ct++)
#pragma unroll
                for (int rt = 0; rt < 4; rt++) acc[ct][rt] = (float4v)0.f;
#pragma unroll
            for (int rt = 0; rt < 4; rt++)
#pragma unroll
                for (int kk = 0; kk < 4; kk++) {
                    const short8 A = *(const short8*)(&Xs[(rt * 16 + lan) * 136 + kk * 32 + quad * 8]);
#pragma unroll
                    for (int ct = 0; ct < 2; ct++)
                        acc[ct][rt] = __builtin_amdgcn_mfma_f32_16x16x32_bf16(
                            A, Bf[ct][kk], acc[ct][rt], 0, 0, 0);
                }
        }
        __syncthreads();
#pragma unroll
        for (int ct = 0; ct < 2; ct++) {
            const int cg = w * 32 + ct * 16 + lan;
            const float bb = bq[cg];
            const float sc = gq[cg] * rsqrtf(1.f + EPS);
            const float sh = betaq[cg];
#pragma unroll
            for (int rt = 0; rt < 4; rt++)
#pragma unroll
                for (int reg = 0; reg < 4; reg++) {
                    float y = (acc[ct][rt][reg] + bb) * sc + sh;
                    y = y > 0.f ? y : 0.f;
                    Xs[(rt * 16 + quad * 4 + reg) * 136 + cg] = f2bf(y);
                }
        }
        __syncthreads();
        {
            short8 Bw[4];
#pragma unroll
            for (int kk = 0; kk < 4; kk++)
                Bw[kk] = *(const short8*)(PWw1b + ((kk * 4 + quad) * 16 + lan) * 8);
            float4v qa = (float4v)0.f;
#pragma unroll
            for (int kk = 0; kk < 4; kk++) {
                const short8 A = *(const short8*)(&Xs[(w * 16 + lan) * 136 + kk * 32 + quad * 8]);
                qa = __builtin_amdgcn_mfma_f32_16x16x32_bf16(A, Bw[kk], qa, 0, 0, 0);
            }
            if (lan < G) {
#pragma unroll
                for (int reg = 0; reg < 4; reg++)
                    Qp[(row0 + w * 16 + quad * 4 + reg) * G + lan] = f2bf(qa[reg]);
            }
        }
    }
}

// ---------------------------------------------------------------------------
// Attention v7: h1 via MFMA (pos staged bf16, K=32-padded); packed bf16 cvt;
// posb overlays pebp+wl (disjoint lifetimes). LDS ~22.9 KB.
// ---------------------------------------------------------------------------
__global__ __launch_bounds__(256) void attn7(
    const u16* __restrict__ vbuf, const u16* __restrict__ Kp,
    const u16* __restrict__ Qp,
    const float* __restrict__ qcoord, const float* __restrict__ ccoord,
    const u16* __restrict__ PWp1b, const float* __restrict__ bp1,
    const float* __restrict__ gp1, const float* __restrict__ betap1,
    const u16* __restrict__ PWp2, const float* __restrict__ bp2,
    const u16* __restrict__ PWp2pb, const float* __restrict__ cw1,
    const float* __restrict__ bw1,
    const float* __restrict__ gw1, const float* __restrict__ betaw1,
    const float* __restrict__ Ww2, const float* __restrict__ bw2,
    const int* __restrict__ knn, float* __restrict__ out)
{
    __shared__ __align__(16) u16 fA[64 * 136];   // h1 -> peb -> val
    __shared__ __align__(16) float ovl[1024];    // posb(4KB) / pebp(2KB)+wl(2KB)
    __shared__ __align__(16) u16 kgs[64 * G];
    __shared__ float qps[QB * G];
    __shared__ float cw1s[G];
    __shared__ int   idxs[64];
    u16*   posb = (u16*)ovl;       // 64 x 32 bf16, zero-padded K
    float* pebp = ovl;             // 64 x 8 fp32
    float* wl   = ovl + 512;       // QB x 16 x 8 fp32

    const int t = threadIdx.x;
    const int w = t >> 6, l = t & 63;
    const int quad = l >> 4, lan = l & 15;
    const int m0 = blockIdx.x * QB;
    const int rsub = t >> 4;
    const int c8 = (t & 15) * 8;

    // ---- P0: v gather (regs), indices, pos -> posb bf16, K'/Q'/cw1 -> LDS ----
    float mfr[4];
    frag_u vg[4];
#pragma unroll
    for (int p = 0; p < 4; p++) {
        const int ii = knn[m0 * KNN + p * 16 + rsub];
        mfr[p] = ii >= 0 ? 1.f : 0.f;
        const size_t i0 = ii >= 0 ? ii : 0;
        vg[p].v = *(const short8*)(vbuf + i0 * C + c8);
    }
    if (t < 64) {
        const int q = t >> 4;
        const int ii = knn[m0 * KNN + t];
        const float mf = ii >= 0 ? 1.f : 0.f;
        const int i0 = ii >= 0 ? ii : 0;
        idxs[t] = ii;
        const float px = (ccoord[i0 * 3 + 0] - qcoord[(m0 + q) * 3 + 0]) * mf;
        const float py = (ccoord[i0 * 3 + 1] - qcoord[(m0 + q) * 3 + 1]) * mf;
        const float pz = (ccoord[i0 * 3 + 2] - qcoord[(m0 + q) * 3 + 2]) * mf;
        frag_u z; z.v = (short8)0;
        z.u[0] = f2bf(px); z.u[1] = f2bf(py); z.u[2] = f2bf(pz);
        const short8 zz = (short8)0;
        *(short8*)(&posb[t * 32])      = z.v;
        *(short8*)(&posb[t * 32 + 8])  = zz;
        *(short8*)(&posb[t * 32 + 16]) = zz;
        *(short8*)(&posb[t * 32 + 24]) = zz;
        *(short8*)(&kgs[t * G]) = *(const short8*)(Kp + (size_t)i0 * G);
    } else if (t < 68) {
        const int p = t - 64;
        frag_u qv;
        qv.v = *(const short8*)(Qp + (size_t)(m0 + p) * G);
#pragma unroll
        for (int j = 0; j < G; j++) qps[p * G + j] = bf2f(qv.u[j]);
    } else if (t < 76) {
        cw1s[t - 68] = cw1[t - 68];
    }
    __syncthreads();

    // ---- P1: h1 = relu(bn(pos @ Wp1 + bp1)) via MFMA -> fA (row-major bf16) ----
    {
        short8 Bp[2];
#pragma unroll
        for (int ct = 0; ct < 2; ct++)
            Bp[ct] = *(const short8*)(PWp1b + (((w * 2 + ct) * 4 + quad) * 16 + lan) * 8);
        float4v ha[2][4];
#pragma unroll
        for (int ct = 0; ct < 2; ct++)
#pragma unroll
            for (int q = 0; q < 4; q++) ha[ct][q] = (float4v)0.f;
#pragma unroll
        for (int q = 0; q < 4; q++) {
            const short8 A = *(const short8*)(&posb[(q * 16 + lan) * 32 + quad * 8]);
#pragma unroll
            for (int ct = 0; ct < 2; ct++)
                ha[ct][q] = __builtin_amdgcn_mfma_f32_16x16x32_bf16(A, Bp[ct], ha[ct][q], 0, 0, 0);
        }
        __syncthreads();   // posb reads done (posb dies; pebp/wl written later)
#pragma unroll
        for (int ct = 0; ct < 2; ct++) {
            const int col = w * 32 + ct * 16 + lan;
            const float sc = gp1[col] * rsqrtf(1.f + EPS);
            const float bb = bp1[col], sh = betap1[col];
#pragma unroll
            for (int q = 0; q < 4; q++)
#pragma unroll
                for (int reg = 0; reg < 4; reg++) {
                    float y = (ha[ct][q][reg] + bb) * sc + sh;
                    y = y > 0.f ? y : 0.f;
                    fA[(q * 16 + quad * 4 + reg) * 136 + col] = f2bf(y);
                }
        }
    }
    __syncthreads();

    // ---- P2: peb = h1 @ Wp2 (32 MFMA) + PEB' = h1 @ Wp2' (4 MFMA) ----
    float4v acc[2][4];
    float4v pp = (float4v)0.f;
    {
        short8 Bf[2][4];
#pragma unroll
        for (int ct = 0; ct < 2; ct++) {
            const int cb = w * 2 + ct;
#pragma unroll
            for (int kk = 0; kk < 4; kk++)
                Bf[ct][kk] = *(const short8*)(PWp2 + (((cb * 4 + kk) * 4 + quad) * 16 + lan) * 8);
        }
#pragma unroll
        for (int ct = 0; ct < 2; ct++)
#pragma unroll
            for (int q = 0; q < 4; q++) acc[ct][q] = (float4v)0.f;
#pragma unroll
        for (int q = 0; q < 4; q++)
#pragma unroll
            for (int kk = 0; kk < 4; kk++) {
                const short8 A = *(const short8*)(&fA[(q * 16 + lan) * 136 + kk * 32 + quad * 8]);
#pragma unroll
                for (int ct = 0; ct < 2; ct++)
                    acc[ct][q] = __builtin_amdgcn_mfma_f32_16x16x32_bf16(
                        A, Bf[ct][kk], acc[ct][q], 0, 0, 0);
            }
        // PEB': wave w -> rows [16w,16w+16)
#pragma unroll
        for (int kk = 0; kk < 4; kk++) {
            const short8 Bp = *(const short8*)(PWp2pb + ((kk * 4 + quad) * 16 + lan) * 8);
            const short8 A = *(const short8*)(&fA[(w * 16 + lan) * 136 + kk * 32 + quad * 8]);
            pp = __builtin_amdgcn_mfma_f32_16x16x32_bf16(A, Bp, pp, 0, 0, 0);
        }
    }
    __syncthreads();   // all h1 reads done

    // ---- P2b: scatter peb (bf16, in place) and PEB' (fp32) ----
    {
        const float bb0 = bp2[w * 32 + lan];
        const float bb1 = bp2[w * 32 + 16 + lan];
#pragma unroll
        for (int ct = 0; ct < 2; ct++)
#pragma unroll
            for (int q = 0; q < 4; q++)
#pragma unroll
                for (int reg = 0; reg < 4; reg++)
                    fA[(q * 16 + quad * 4 + reg) * 136 + w * 32 + ct * 16 + lan] =
                        f2bf(acc[ct][q][reg] + (ct ? bb1 : bb0));
        if (lan < G) {
#pragma unroll
            for (int reg = 0; reg < 4; reg++)
                pebp[(w * 16 + quad * 4 + reg) * G + lan] = pp[reg];
        }
    }
    __syncthreads();

    // ---- P3: val = vg*mf + peb -> fA (in place); logits -> wl ----
    {
#pragma unroll
        for (int p = 0; p < 4; p++) {
            const int r = p * 16 + rsub;
            const float mf = mfr[p];
            frag_u peb, valv;
            peb.v = *(const short8*)(&fA[r * 136 + c8]);
#pragma unroll
            for (int h = 0; h < 4; h++)
                valv.d[h] = pkbf(fmaf(bf2f(vg[p].u[2 * h]),     mf, bf2f(peb.u[2 * h])),
                                 fmaf(bf2f(vg[p].u[2 * h + 1]), mf, bf2f(peb.u[2 * h + 1])));
            *(short8*)(&fA[r * 136 + c8]) = valv.v;   // exclusive slot
        }
    }
    if (t < 64) {
        const int q = t >> 4, j = t & 15;
        const float mf = idxs[t] >= 0 ? 1.f : 0.f;
#pragma unroll
        for (int g = 0; g < G; g++) {
            const float L = bf2f(kgs[t * G + g]) * mf - qps[q * G + g]
                          + pebp[t * G + g] + cw1s[g] + bw1[g];
            const float y = L * (gw1[g] * rsqrtf(1.f + EPS)) + betaw1[g];
            wl[q * 128 + j * G + g] = y > 0.f ? y : 0.f;
        }
    }
    __syncthreads();

    // ---- P5: logits = hw @ Ww2 + bw2; softmax; * mask (wl in place) ----
    if (t < QB * G) {
        const int q = t >> 3, g2 = t & 7;
        float w2c[G];
#pragma unroll
        for (int g = 0; g < G; g++) w2c[g] = Ww2[g * G + g2];
        const float bb = bw2[g2];
        float lg[KNN], mx = -1e30f;
#pragma unroll
        for (int j = 0; j < KNN; j++) {
            float a = bb;
#pragma unroll
            for (int g = 0; g < G; g++) a = fmaf(wl[q * 128 + j * 8 + g], w2c[g], a);
            lg[j] = a;
            mx = fmaxf(mx, a);
        }
        float sum = 0.f;
#pragma unroll
        for (int j = 0; j < KNN; j++) { lg[j] = __expf(lg[j] - mx); sum += lg[j]; }
        const float inv = 1.f / sum;
#pragma unroll
        for (int j = 0; j < KNN; j++) {
            const float mf = idxs[q * 16 + j] >= 0 ? 1.f : 0.f;
            wl[q * 128 + j * 8 + g2] = lg[j] * inv * mf;
        }
    }
    __syncthreads();

    // ---- P6: out[q][c] = sum_j val[j][c] * w[j][c>>4] ----
#pragma unroll
    for (int i = 0; i < 2; i++) {
        const int e = t + 256 * i;
        const int q = e >> 7, c = e & 127, g = c >> 4;
        float a = 0.f;
#pragma unroll
        for (int j = 0; j < KNN; j++)
            a = fmaf(bf2f(fA[(q * 16 + j) * 136 + c]), wl[q * 128 + j * 8 + g], a);
        out[(size_t)(m0 + q) * C + c] = a;
    }
}

// ---------------------------------------------------------------------------
extern "C" void kernel_launch(void* const* d_in, const int* in_sizes, int n_in,
                              void* d_out, int out_size, void* d_ws, size_t ws_size,
                              hipStream_t stream)
{
    const float* query_feat    = (const float*)d_in[0];
    const float* context_feat  = (const float*)d_in[1];
    const float* query_coord   = (const float*)d_in[2];
    const float* context_coord = (const float*)d_in[3];
    const float* Wq    = (const float*)d_in[4];
    const float* bq    = (const float*)d_in[5];
    const float* gq    = (const float*)d_in[6];
    const float* betaq = (const float*)d_in[7];
    const float* Wk    = (const float*)d_in[8];
    const float* bk    = (const float*)d_in[9];
    const float* gk    = (const float*)d_in[10];
    const float* betak = (const float*)d_in[11];
    const float* Wv    = (const float*)d_in[12];
    const float* bv    = (const float*)d_in[13];
    const float* Wp1   = (const float*)d_in[14];
    const float* bp1   = (const float*)d_in[15];
    const float* gp1   = (const float*)d_in[16];
    const float* betap1= (const float*)d_in[17];
    const float* Wp2   = (const float*)d_in[18];
    const float* bp2   = (const float*)d_in[19];
    const float* Ww1   = (const float*)d_in[20];
    const float* bw1   = (const float*)d_in[21];
    const float* gw1   = (const float*)d_in[22];
    const float* betaw1= (const float*)d_in[23];
    const float* Ww2   = (const float*)d_in[24];
    const float* bw2   = (const float*)d_in[25];
    const int*   knn   = (const int*)d_in[26];

    const int M = in_sizes[0] / C;   // 16384
    const int N = in_sizes[1] / C;   // 131072

    // workspace: v (N*C bf16) | K' (N*G) | Q' (M*G) | prepped weights | cw1
    u16* vb = (u16*)d_ws;
    u16* Kp = vb + (size_t)N * C;
    u16* Qp = Kp + (size_t)N * G;
    u16* pw = Qp + (size_t)M * G;
    u16* pWk    = pw;
    u16* pWv    = pw + 16384;
    u16* pWq    = pw + 2 * 16384;
    u16* pWp2   = pw + 3 * 16384;
    u16* pWw1b  = pw + 4 * 16384;
    u16* pWp2pb = pw + 4 * 16384 + 4096;
    u16* pWp1b  = pw + 4 * 16384 + 2 * 4096;
    float* cw1  = (float*)(pw + 4 * 16384 + 3 * 4096);

    prep_w<<<19, 256, 0, stream>>>(Wk, Wv, Wq, Wp2, Ww1, Wp1, bp2, pw, cw1);
    proj_all<<<N / 64 + M / 64, 256, 0, stream>>>(
        context_feat, query_feat,
        pWk, bk, gk, betak, pWv, bv,
        pWq, bq, gq, betaq, pWw1b,
        vb, Kp, Qp, N / 64);
    attn7<<<M / QB, 256, 0, stream>>>(vb, Kp, Qp, query_coord, context_coord,
                                      pWp1b, bp1, gp1, betap1, pWp2, bp2,
                                      pWp2pb, cw1, bw1, gw1, betaw1, Ww2, bw2,
                                      knn, (float*)d_out);
}